// Round 2
// baseline (17848.862 us; speedup 1.0000x reference)
//
#include <hip/hip_runtime.h>
#include <hip/hip_bf16.h>
#include <hip/hip_cooperative_groups.h>
#include <math.h>

namespace cg = cooperative_groups;

#define T_STEPS 256
#define B_SZ 64
#define DIN 512
#define H_SZ 1024
#define CH_SZ 2048
#define G3 6144
#define DOUT 512
#define TB 16384

typedef __attribute__((ext_vector_type(4))) float f32x4;
typedef __attribute__((ext_vector_type(8))) short s16x8;
typedef __attribute__((ext_vector_type(4))) short s16x4;
typedef __attribute__((ext_vector_type(8))) __bf16 bf16x8;

__device__ __forceinline__ unsigned short f2bf(float f) {
  unsigned u = __builtin_bit_cast(unsigned, f);
  u += 0x7fffu + ((u >> 16) & 1u);   // RNE
  return (unsigned short)(u >> 16);
}
__device__ __forceinline__ float bf2f(unsigned short h) {
  unsigned u = ((unsigned)h) << 16;
  return __builtin_bit_cast(float, u);
}
__device__ __forceinline__ f32x4 mfma16(s16x8 a, s16x8 b, f32x4 c) {
  return __builtin_amdgcn_mfma_f32_16x16x32_bf16(
      __builtin_bit_cast(bf16x8, a), __builtin_bit_cast(bf16x8, b), c, 0, 0, 0);
}

// ---------------------------------------------------------------------------
// C[M,N] = act(A[M,K] @ B[N,K]^T + bias[N]) ; unchanged from round 1 (works).
// ---------------------------------------------------------------------------
template<bool AF32, int ACT, bool OBF>
__global__ __launch_bounds__(256, 2)
void gemm_bt(const void* __restrict__ Ap, long lda,
             const unsigned short* __restrict__ Bp,
             const float* __restrict__ bias,
             float* __restrict__ Cf, unsigned short* __restrict__ Cb, long ldc,
             int K)
{
  __shared__ unsigned short sA[128 * 40];
  __shared__ unsigned short sB[128 * 40];
  const int tid  = threadIdx.x;
  const int lane = tid & 63;
  const int wave = tid >> 6;
  const int wm = wave & 1, wn = wave >> 1;
  const int l16 = lane & 15, quad = lane >> 4;
  const long m0 = (long)blockIdx.x * 128;
  const long n0 = (long)blockIdx.y * 128;
  const int srow = tid >> 1;
  const int sseg = (tid & 1) << 4;

  f32x4 acc[4][4] = {};

  for (int k0 = 0; k0 < K; k0 += 32) {
    if constexpr (AF32) {
      const float* A = (const float*)Ap + (m0 + srow) * lda + (k0 + sseg);
      f32x4 v0 = *(const f32x4*)(A + 0);
      f32x4 v1 = *(const f32x4*)(A + 4);
      f32x4 v2 = *(const f32x4*)(A + 8);
      f32x4 v3 = *(const f32x4*)(A + 12);
      s16x8 p0, p1;
      p0[0] = (short)f2bf(v0.x); p0[1] = (short)f2bf(v0.y);
      p0[2] = (short)f2bf(v0.z); p0[3] = (short)f2bf(v0.w);
      p0[4] = (short)f2bf(v1.x); p0[5] = (short)f2bf(v1.y);
      p0[6] = (short)f2bf(v1.z); p0[7] = (short)f2bf(v1.w);
      p1[0] = (short)f2bf(v2.x); p1[1] = (short)f2bf(v2.y);
      p1[2] = (short)f2bf(v2.z); p1[3] = (short)f2bf(v2.w);
      p1[4] = (short)f2bf(v3.x); p1[5] = (short)f2bf(v3.y);
      p1[6] = (short)f2bf(v3.z); p1[7] = (short)f2bf(v3.w);
      *(s16x8*)&sA[srow * 40 + sseg]     = p0;
      *(s16x8*)&sA[srow * 40 + sseg + 8] = p1;
    } else {
      const unsigned short* A = (const unsigned short*)Ap + (m0 + srow) * lda + (k0 + sseg);
      *(s16x8*)&sA[srow * 40 + sseg]     = *(const s16x8*)(A);
      *(s16x8*)&sA[srow * 40 + sseg + 8] = *(const s16x8*)(A + 8);
    }
    {
      const unsigned short* Bq = Bp + (n0 + srow) * (long)K + (k0 + sseg);
      *(s16x8*)&sB[srow * 40 + sseg]     = *(const s16x8*)(Bq);
      *(s16x8*)&sB[srow * 40 + sseg + 8] = *(const s16x8*)(Bq + 8);
    }
    __syncthreads();
    s16x8 af[4], bfr[4];
#pragma unroll
    for (int i = 0; i < 4; ++i) {
      af[i]  = *(const s16x8*)&sA[(wm * 64 + i * 16 + l16) * 40 + quad * 8];
      bfr[i] = *(const s16x8*)&sB[(wn * 64 + i * 16 + l16) * 40 + quad * 8];
    }
#pragma unroll
    for (int mi = 0; mi < 4; ++mi)
#pragma unroll
      for (int ni = 0; ni < 4; ++ni)
        acc[mi][ni] = mfma16(af[mi], bfr[ni], acc[mi][ni]);
    __syncthreads();
  }

#pragma unroll
  for (int mi = 0; mi < 4; ++mi) {
#pragma unroll
    for (int ni = 0; ni < 4; ++ni) {
      const long n = n0 + wn * 64 + ni * 16 + l16;
      const float bv = bias[n];
#pragma unroll
      for (int i = 0; i < 4; ++i) {
        const long m = m0 + wm * 64 + mi * 16 + quad * 4 + i;
        float v = acc[mi][ni][i] + bv;
        if constexpr (ACT == 1) v = v > 0.f ? v : expm1f(v);
        if constexpr (ACT == 2) v = fmaxf(v, 0.f) + log1pf(expf(-fabsf(v))) + 0.1f;
        if constexpr (OBF) Cb[m * ldc + n] = f2bf(v);
        else               Cf[m * ldc + n] = v;
      }
    }
  }
}

// ---------------------------------------------------------------------------
// Persistent GRU recurrence. 256 blocks x 256 threads, cooperative launch.
// Block b owns units jb=b*8..+8 (x3 gates = 24 Whh rows) resident in 96 KB LDS
// for all 256 steps (loaded once). Per step: gh = h @ Whh_slice^T via MFMA
// (a-frags direct from global bf16 h ping-pong; no barriers in K-loop),
// fused gate epilogue with fp32 running h held in registers, grid.sync().
// LDS layout: row r (0..23) = gate(r>>3), unit(r&7); 16B chunks XOR-swizzled:
// phys_chunk = log_chunk ^ (r&7)  -> uniform bank load for both MFMA B-frags.
// ---------------------------------------------------------------------------
__global__ __launch_bounds__(256, 1)
void gru_persist(const unsigned short* __restrict__ Whhb,  // [6144,2048] bf16
                 const unsigned short* __restrict__ gxb,   // [T,64,6144] bf16
                 const float* __restrict__ bhh,            // [6144]
                 unsigned short* __restrict__ hA,          // [64,2048] bf16, zeroed
                 unsigned short* __restrict__ hB,          // [64,2048] bf16
                 float* __restrict__ hid)                  // [T,64,2048] fp32
{
  extern __shared__ unsigned short sW[];   // 24 * 2048 bf16 = 96 KB
  const int tid  = threadIdx.x;
  const int lane = tid & 63;
  const int wave = tid >> 6;
  const int l16 = lane & 15, quad = lane >> 4;
  const int jb = blockIdx.x * 8;

  // stage Whh slice once: iteration 'it' = LDS row; 256 threads x 8 elems = one row
  for (int it = 0; it < 24; ++it) {
    const int gate = it >> 3, u = it & 7;
    const unsigned short* src = Whhb + ((long)(gate * CH_SZ + jb + u)) * CH_SZ + tid * 8;
    s16x8 v = *(const s16x8*)src;
    *(s16x8*)((char*)sW + it * 4096 + ((tid ^ (it & 7)) << 4)) = v;
  }
  __syncthreads();

  const int u = l16 & 7;          // unit this thread handles in epilogue (l16<8)
  const int j = jb + u;
  const float br_ = bhh[j], bz_ = bhh[CH_SZ + j], bn_ = bhh[2 * CH_SZ + j];

  const long arow_off = (long)(wave * 16 + l16) * CH_SZ + quad * 8;
  const int b1base = l16 * 4096;            // rows 0..15: [r u0-7 | z u0-7]
  const int b2base = (16 + u) * 4096;       // rows 16..23: n u0-7 (dup across halves)
  const int rr = l16 & 7;

  float hold[4] = {0.f, 0.f, 0.f, 0.f};     // fp32 running h for (m=wave*16+quad*4+i, j)

  cg::grid_group grid = cg::this_grid();

  for (int t = 0; t < T_STEPS; ++t) {
    const unsigned short* hp = (t & 1) ? hB : hA;
    unsigned short*       hn = (t & 1) ? hA : hB;
    const unsigned short* gx = gxb + (long)t * (B_SZ * G3);

    f32x4 aRZ = {}, aN = {};
#pragma unroll 4
    for (int k0 = 0; k0 < CH_SZ; k0 += 32) {
      s16x8 a = *(const s16x8*)(hp + arow_off + k0);
      const int sw = (((k0 >> 3) + quad) ^ rr) << 4;
      s16x8 b1 = *(const s16x8*)((const char*)sW + b1base + sw);
      s16x8 b2 = *(const s16x8*)((const char*)sW + b2base + sw);
      aRZ = mfma16(a, b1, aRZ);
      aN  = mfma16(a, b2, aN);
    }

    // z for unit u sits in lane l16+8 (same quad): pull with shfl_xor(8)
    float zsh[4];
#pragma unroll
    for (int i = 0; i < 4; ++i) zsh[i] = __shfl_xor(aRZ[i], 8, 64);

    if (l16 < 8) {
#pragma unroll
      for (int i = 0; i < 4; ++i) {
        const int m = wave * 16 + quad * 4 + i;
        const long g = (long)m * G3;
        const float xr = bf2f(gx[g + j]);
        const float xz = bf2f(gx[g + CH_SZ + j]);
        const float xn = bf2f(gx[g + 2 * CH_SZ + j]);
        const float r = 1.f / (1.f + expf(-(xr + aRZ[i] + br_)));
        const float z = 1.f / (1.f + expf(-(xz + zsh[i] + bz_)));
        const float n = tanhf(xn + r * (aN[i] + bn_));
        const float hv = (1.f - z) * n + z * hold[i];
        hold[i] = hv;
        hid[((long)t * B_SZ + m) * CH_SZ + j] = hv;
        hn[(long)m * CH_SZ + j] = f2bf(hv);
      }
    }
    __threadfence();
    grid.sync();
  }
}

__global__ void cast_f32_bf16(const float* __restrict__ s, unsigned short* __restrict__ d, long n) {
  long i = ((long)blockIdx.x * blockDim.x + threadIdx.x) * 4;
  if (i + 3 < n) {
    f32x4 v = *(const f32x4*)(s + i);
    s16x4 p;
    p[0] = (short)f2bf(v.x); p[1] = (short)f2bf(v.y);
    p[2] = (short)f2bf(v.z); p[3] = (short)f2bf(v.w);
    *(s16x4*)(d + i) = p;
  }
}

__global__ void zero_u32(unsigned int* p, int n) {
  int i = blockIdx.x * blockDim.x + threadIdx.x;
  if (i < n) p[i] = 0u;
}

extern "C" void kernel_launch(void* const* d_in, const int* in_sizes, int n_in,
                              void* d_out, int out_size, void* d_ws, size_t ws_size,
                              hipStream_t stream)
{
  const float* x    = (const float*)d_in[0];
  const float* We   = (const float*)d_in[1];
  const float* be   = (const float*)d_in[2];
  const float* Wih  = (const float*)d_in[3];
  const float* bih  = (const float*)d_in[4];
  const float* Whh  = (const float*)d_in[5];
  const float* bhh  = (const float*)d_in[6];
  const float* Wmu  = (const float*)d_in[7];
  const float* bmu  = (const float*)d_in[8];
  const float* Wsig = (const float*)d_in[9];
  const float* bsig = (const float*)d_in[10];

  float* out = (float*)d_out;
  float* mu  = out;
  float* sg  = out + (long)TB * DOUT;
  float* hid = out + 2L * TB * DOUT;

  char* w = (char*)d_ws;
  unsigned short* Web  = (unsigned short*)w; w += (long)H_SZ * DIN * 2;
  unsigned short* Wihb = (unsigned short*)w; w += (long)G3 * H_SZ * 2;
  unsigned short* Whhb = (unsigned short*)w; w += (long)G3 * CH_SZ * 2;
  unsigned short* Wmub = (unsigned short*)w; w += (long)DOUT * H_SZ * 2;
  unsigned short* Wsgb = (unsigned short*)w; w += (long)DOUT * H_SZ * 2;
  unsigned short* xeb  = (unsigned short*)w; w += (long)TB * H_SZ * 2;
  unsigned short* gxb  = (unsigned short*)w; w += (long)TB * G3 * 2;
  unsigned short* hbA  = (unsigned short*)w; w += (long)B_SZ * CH_SZ * 2;
  unsigned short* hbB  = (unsigned short*)w; w += (long)B_SZ * CH_SZ * 2;

  auto cast = [&](const float* s, unsigned short* d, long n) {
    int blocks = (int)((n / 4 + 255) / 256);
    cast_f32_bf16<<<blocks, 256, 0, stream>>>(s, d, n);
  };
  cast(We,   Web,  (long)H_SZ * DIN);
  cast(Wih,  Wihb, (long)G3 * H_SZ);
  cast(Whh,  Whhb, (long)G3 * CH_SZ);
  cast(Wmu,  Wmub, (long)DOUT * H_SZ);
  cast(Wsig, Wsgb, (long)DOUT * H_SZ);
  {
    int n = B_SZ * CH_SZ * 2 / 4;
    zero_u32<<<(n + 255) / 256, 256, 0, stream>>>((unsigned int*)hbA, n);
  }

  // enc: xe = elu(x @ We^T + be) -> bf16 [TB, H]
  gemm_bt<true, 1, true><<<dim3(TB / 128, H_SZ / 128), 256, 0, stream>>>(
      x, (long)DIN, Web, be, nullptr, xeb, (long)H_SZ, DIN);

  // gx = xe @ Wih^T + bih -> bf16 [TB, 6144]
  gemm_bt<false, 0, true><<<dim3(TB / 128, G3 / 128), 256, 0, stream>>>(
      xeb, (long)H_SZ, Wihb, bih, nullptr, gxb, (long)G3, H_SZ);

  // recurrence: one persistent cooperative kernel, 96 KB dynamic LDS
  {
    const int lds_bytes = 24 * CH_SZ * 2;
    hipFuncSetAttribute((const void*)gru_persist,
                        hipFuncAttributeMaxDynamicSharedMemorySize, lds_bytes);
    void* kargs[] = { (void*)&Whhb, (void*)&gxb, (void*)&bhh,
                      (void*)&hbA, (void*)&hbB, (void*)&hid };
    hipLaunchCooperativeKernel((const void*)gru_persist, dim3(256), dim3(256),
                               kargs, lds_bytes, stream);
  }

  // heads
  gemm_bt<true, 1, false><<<dim3(TB / 128, DOUT / 128), 256, 0, stream>>>(
      hid, (long)CH_SZ, Wmub, bmu, mu, nullptr, (long)DOUT, H_SZ);
  gemm_bt<true, 2, false><<<dim3(TB / 128, DOUT / 128), 256, 0, stream>>>(
      hid + H_SZ, (long)CH_SZ, Wsgb, bsig, sg, nullptr, (long)DOUT, H_SZ);
}